// Round 1
// 97.962 us; speedup vs baseline: 1.0040x; 1.0040x over previous
//
#include <hip/hip_runtime.h>

#define HH 480
#define WW 640
#define HW (HH * WW)
#define NC 3
#define NVX 128            // W/SKIP
#define NVY 96             // H/SKIP
#define NV (NVX * NVY)     // 12288
#define NBX 80
#define NBY 60
#define NB (NBX * NBY)     // 4800
#define NSL 48                         // point slices (NV / 256)
#define BINBLOCKS ((NB + 255) / 256)   // 19

// ---------------- kernel 1: fused gather + per-class stable compaction + vote ----------------
// Grid (BINBLOCKS, NSL) x 256. Each block re-gathers its slice's 256 sample points
// (redundant across the 19 bin-blocks; L2/L3-hot), stable-partitions them by class
// into LDS (class1 first, class2 after; ascending original index within each class,
// which preserves the reference segment_sum fold order per class), then votes.
// No atomics, no zero-init: each block writes partial[slice][bin] = {h1,d1,h2,d2}.
//
// Inlier test: ux,uy are pre-scaled by 2 so cos>0.5 <=> dot>0 && dot^2 > nx
// (saves the 0.25*nx multiply). Borderline pairs (|s| < nx*8e-5, same relative
// band as the previous 2e-5 band on the 4x-smaller s) recompute the reference's
// exact IEEE sequence with ux = 0.5f*a.z (exact, power-of-2 scale).
__global__ void vote_fused(const int* __restrict__ label,
                           const float* __restrict__ vert,
                           float4* __restrict__ partial,     // [NSL][NB]
                           int2* __restrict__ sliceCounts) { // [NSL]
    __shared__ float4 shA[256];   // vx, vy, 2*ux, 2*uy
    __shared__ float  shD[256];   // dist
    __shared__ int sw1[4], sw2[4];

    const int tid = threadIdx.x;
    const int slice = blockIdx.y;
    const int i = slice * 256 + tid;       // point index in [0, NV)
    const int iy = i >> 7;                 // NVX = 128
    const int ix = i & (NVX - 1);
    const int pix = (5 * iy) * WW + 5 * ix;
    const int vl = label[pix];
    const float* base = vert + (size_t)(vl * 3) * HW + pix;
    const float ux = base[0];
    const float uy = base[HW];
    const float dist = base[(size_t)2 * HW];

    const int lane = tid & 63, w = tid >> 6;
    const unsigned long long lt = (1ull << lane) - 1ull;
    const unsigned long long m1 = __ballot(vl == 1);
    const unsigned long long m2 = __ballot(vl == 2);
    if (lane == 0) { sw1[w] = __popcll(m1); sw2[w] = __popcll(m2); }
    __syncthreads();
    const int n1 = sw1[0] + sw1[1] + sw1[2] + sw1[3];
    const int n2 = sw2[0] + sw2[1] + sw2[2] + sw2[3];
    int o1 = 0, o2 = 0;
    for (int k = 0; k < w; ++k) { o1 += sw1[k]; o2 += sw2[k]; }
    if (vl == 1) {
        int p = o1 + __popcll(m1 & lt);
        shA[p] = make_float4((float)(5 * ix), (float)(5 * iy), 2.0f * ux, 2.0f * uy);
        shD[p] = dist;
    } else if (vl == 2) {
        int p = n1 + o2 + __popcll(m2 & lt);
        shA[p] = make_float4((float)(5 * ix), (float)(5 * iy), 2.0f * ux, 2.0f * uy);
        shD[p] = dist;
    }
    if (blockIdx.x == 0 && tid == 0) sliceCounts[slice] = make_int2(n1, n2);
    __syncthreads();

    const int b = blockIdx.x * 256 + tid;
    const float bxf = (float)(4 + 8 * (b % NBX));
    const float byf = (float)(4 + 8 * (b / NBX));
    float h1 = 0.f, d1 = 0.f, h2 = 0.f, d2 = 0.f;

    const int e1 = __builtin_amdgcn_readfirstlane(n1);       // wave-uniform bounds
    const int e2 = __builtin_amdgcn_readfirstlane(n1 + n2);  // -> SGPR loop control

#define PAIR_BODY(HACC, DACC)                                                        \
    {                                                                                \
        float4 a = shA[j];                                                           \
        float ddx = bxf - a.x;                                                       \
        float ddy = byf - a.y;                                                       \
        float nx  = __builtin_fmaf(ddx, ddx, __builtin_fmaf(ddy, ddy, 1e-6f));       \
        float dot = __builtin_fmaf(ddx, a.z, ddy * a.w);                             \
        float s   = __builtin_fmaf(dot, dot, -nx);                                   \
        bool v = (dot > 0.0f) & (s > 0.0f);                                          \
        if (__builtin_expect((dot > 0.0f) && (fabsf(s) < nx * 8e-5f), 0)) {          \
            float nxe  = __fadd_rn(__fadd_rn(__fmul_rn(ddx, ddx),                    \
                                             __fmul_rn(ddy, ddy)), 1e-6f);           \
            float inve = __fdiv_rn(1.0f, __fsqrt_rn(nxe));                           \
            float dote = __fadd_rn(__fmul_rn(ddx, 0.5f * a.z),                       \
                                   __fmul_rn(ddy, 0.5f * a.w));                      \
            v = __fmul_rn(dote, inve) > 0.5f;                                        \
        }                                                                            \
        float m = v ? 1.0f : 0.0f;                                                   \
        HACC += m;                                                                   \
        DACC = __builtin_fmaf(m, shD[j], DACC);                                      \
    }

#pragma unroll 4
    for (int j = 0; j < e1; ++j) PAIR_BODY(h1, d1)
#pragma unroll 4
    for (int j = e1; j < e2; ++j) PAIR_BODY(h2, d2)
#undef PAIR_BODY

    if (b < NB) partial[slice * NB + b] = make_float4(h1, d1, h2, d2);
}

// ---------------- kernel 2: slice reduction + per-block argmax candidates ----------------
// Folds the 48 slice partials in ascending slice order (left fold, matching the
// reference's ascending-index segment_sum order), writes hough (incl. zero class-0
// row) and dsum, and emits one packed (value_bits, NB-1-i) argmax candidate per
// block per class (max value wins, ties -> smallest index).
__global__ void reduce_vote(const float4* __restrict__ partial,
                            float* __restrict__ hough,   // out + 18, [NC][NB]
                            float* __restrict__ dsum,    // [2][NB]
                            unsigned long long* __restrict__ cand) { // [BINBLOCKS][2]
    __shared__ unsigned long long sk1[256], sk2[256];
    const int tid = threadIdx.x;
    const int b = blockIdx.x * 256 + tid;
    unsigned long long k1 = 0ull, k2 = 0ull;
    if (b < NB) {
        float h1 = 0.f, d1 = 0.f, h2 = 0.f, d2 = 0.f;
#pragma unroll 8
        for (int s = 0; s < NSL; ++s) {
            float4 p = partial[s * NB + b];
            h1 += p.x; d1 += p.y; h2 += p.z; d2 += p.w;
        }
        hough[b] = 0.0f;
        hough[NB + b] = h1;
        hough[2 * NB + b] = h2;
        dsum[b] = d1;
        dsum[NB + b] = d2;
        const unsigned long long idx = (unsigned long long)(unsigned)(NB - 1 - b);
        k1 = ((unsigned long long)__float_as_uint(h1) << 32) | idx;
        k2 = ((unsigned long long)__float_as_uint(h2) << 32) | idx;
    }
    sk1[tid] = k1; sk2[tid] = k2;
    __syncthreads();
    for (int s = 128; s > 0; s >>= 1) {
        if (tid < s) {
            if (sk1[tid + s] > sk1[tid]) sk1[tid] = sk1[tid + s];
            if (sk2[tid + s] > sk2[tid]) sk2[tid] = sk2[tid + s];
        }
        __syncthreads();
    }
    if (tid == 0) {
        cand[blockIdx.x * 2]     = sk1[0];
        cand[blockIdx.x * 2 + 1] = sk2[0];
    }
}

// ---------------- kernel 3: final argmax + counts + ROI math (1 block, 1 wave) ----------------
__global__ void finalize(const unsigned long long* __restrict__ cand,
                         const int2* __restrict__ sliceCounts,
                         const float* __restrict__ dsum,
                         const float* __restrict__ meta,
                         const float* __restrict__ extents,
                         float* __restrict__ rois) {
    const int tid = threadIdx.x;  // 64 threads = 1 wave
    unsigned long long k1 = (tid < BINBLOCKS) ? cand[tid * 2]     : 0ull;
    unsigned long long k2 = (tid < BINBLOCKS) ? cand[tid * 2 + 1] : 0ull;
    int cn1 = 0, cn2 = 0;
    if (tid < NSL) { int2 c = sliceCounts[tid]; cn1 = c.x; cn2 = c.y; }
    for (int off = 32; off > 0; off >>= 1) {
        unsigned long long o1 = __shfl_xor(k1, off);
        unsigned long long o2 = __shfl_xor(k2, off);
        if (o1 > k1) k1 = o1;
        if (o2 > k2) k2 = o2;
        cn1 += __shfl_xor(cn1, off);
        cn2 += __shfl_xor(cn2, off);
    }
    if (tid < NC) {
        const int c = tid;
        float votes; int peak;
        if (c == 0) { votes = 0.0f; peak = 0; }
        else {
            unsigned long long k = (c == 1) ? k1 : k2;
            votes = __uint_as_float((unsigned)(k >> 32));
            peak = NB - 1 - (int)(k & 0xffffffffull);
        }
        const float cntf = (c == 0) ? (float)(NV - cn1 - cn2)
                                    : ((c == 1) ? (float)cn1 : (float)cn2);
        const float ds = (c == 0) ? 0.0f : dsum[(c - 1) * NB + peak];
        const float depth = __fdiv_rn(ds, fmaxf(votes, 1.0f));
        const float cx = (float)(4 + 8 * (peak % NBX));
        const float cy = (float)(4 + 8 * (peak / NBX));
        const float score = __fdiv_rn(votes, fmaxf(cntf, 1.0f));
        const int valid = (cntf > 5.0f) && (score > 0.3f);
        const float fx = meta[0], fy = meta[4];
        const float e0 = extents[c * 3 + 0];
        const float e1 = extents[c * 3 + 1];
        const float e2 = extents[c * 3 + 2];
        const float diag = __fsqrt_rn(__fadd_rn(
            __fadd_rn(__fmul_rn(e0, e0), __fmul_rn(e1, e1)), __fmul_rn(e2, e2)));
        const float sz = fmaxf(fabsf(depth), 0.001f);
        const float bw = __fdiv_rn(fabsf(__fmul_rn(diag, fx)), sz);
        const float bh = __fdiv_rn(fabsf(__fmul_rn(diag, fy)), sz);
        rois[c * 6 + 0] = (float)c;
        rois[c * 6 + 1] = cx - bw * 0.5f;
        rois[c * 6 + 2] = cy - bh * 0.5f;
        rois[c * 6 + 3] = cx + bw * 0.5f;
        rois[c * 6 + 4] = cy + bh * 0.5f;
        rois[c * 6 + 5] = valid ? score : 0.0f;
    }
}

extern "C" void kernel_launch(void* const* d_in, const int* in_sizes, int n_in,
                              void* d_out, int out_size, void* d_ws, size_t ws_size,
                              hipStream_t stream) {
    const int* label = (const int*)d_in[0];
    const float* vert = (const float*)d_in[1];
    const float* meta = (const float*)d_in[2];
    const float* extents = (const float*)d_in[3];
    float* out = (float*)d_out;

    char* ws = (char*)d_ws;
    float4* partial = (float4*)ws;                                       // 3,686,400 B
    float* dsum = (float*)(ws + (size_t)NSL * NB * 16);                  //    38,400 B
    unsigned long long* cand =
        (unsigned long long*)(ws + (size_t)NSL * NB * 16 + 2 * NB * 4);  //       304 B
    int2* sliceCounts =
        (int2*)(ws + (size_t)NSL * NB * 16 + 2 * NB * 4 + 2 * BINBLOCKS * 8); // 384 B

    float* hough = out + NC * 6;  // 3*NB floats; rois occupy out[0..17]

    vote_fused<<<dim3(BINBLOCKS, NSL), 256, 0, stream>>>(label, vert, partial, sliceCounts);
    reduce_vote<<<BINBLOCKS, 256, 0, stream>>>(partial, hough, dsum, cand);
    finalize<<<1, 64, 0, stream>>>(cand, sliceCounts, dsum, meta, extents, out);
}